// Round 3
// baseline (718.709 us; speedup 1.0000x reference)
//
#include <hip/hip_runtime.h>

// Scaled dot-product attention, B=8 H=12 S=1024 D=64, fp32 in/out.
// Outputs (concatenated in d_out): probs (B,H,S,S) then context (B,H,S,D).
//
// v4: S^T-layout rewrite.
//  - QK^T computed as S^T = K @ Q^T (A=K rows, B=Q^T). Each lane then holds
//    scores for ONE q-row (c16) at keys quad*4+i+16*mt. Softmax is in-lane
//    + 2 shuffles + 4-wave LDS combine. Probs stores are f32x4 of 4
//    consecutive keys (coalesced, no transpose). The PV A-fragment IS this
//    register layout (slot map kappa(t,q'*8+j) = 32t + q'*4 + (j&3) + 16*(j>>2)),
//    so P never goes through LDS: the 132KB pl buffer and ALL its bank
//    conflicts are gone.
//  - Pre-pass kernel writes Kbf16 (row-major) and VTbf16 ([bh][d][key]) into
//    d_ws (25.2 MB): kills per-block K f32->bf16 conversion (v3's 4x
//    regression) and makes PV B-frags two b64 loads from VT rows.
//    Fallback path (ws too small): convert K on the fly + scalar V loads.
//  - 256-thread blocks (4 waves, wave w owns keys w*256..+255), 16 q-rows.
//    LDS ~21.5 KB, VGPR target <=128 -> ~4 blocks/CU, 4 barriers total.
//  - PV partials (16q x 64d per wave) reduced via 18KB LDS, then coalesced
//    f32x4 context stores. Probs stored before PV (frees acc regs); drains
//    are covered by co-resident blocks.
//  - XCD-clustered bid decode: 12 whole bh per XCD -> K/VT L2-resident.

#define SLEN 1024
#define DHEAD 64
#define NBH 96
#define QROWS 16

typedef __attribute__((ext_vector_type(4))) float f32x4;
typedef __attribute__((ext_vector_type(4))) __bf16 bf16x4;
typedef __attribute__((ext_vector_type(8))) __bf16 bf16x8;

union BF8 { bf16x8 v; bf16x4 h[2]; };

#define KB_ELEMS ((size_t)NBH * SLEN * DHEAD)   // 6291456
#define WS_BYTES (KB_ELEMS * 2 * 2)             // 25165824

// ---------------- pre-pass: Kbf16 + VT bf16 into workspace ----------------
__global__ __launch_bounds__(256)
void prepass(const float* __restrict__ Kp, const float* __restrict__ Vp,
             __bf16* __restrict__ Kb, __bf16* __restrict__ VTb) {
  __shared__ float tf[64][68];
  const int b = blockIdx.x, t = threadIdx.x;
  if (b < 1536) {
    // V transpose: bh = b>>4, 64-key chunk kc = b&15 -> VTb[bh][d][key]
    const int bh = b >> 4, kc = b & 15;
    const float* Vg = Vp + ((size_t)bh * SLEN + (size_t)kc * 64) * DHEAD;
    #pragma unroll
    for (int i = 0; i < 4; ++i) {
      int r = i * 16 + (t >> 4), d0 = (t & 15) * 4;
      f32x4 v = *(const f32x4*)(Vg + (size_t)r * DHEAD + d0);
      #pragma unroll
      for (int j = 0; j < 4; ++j) tf[r][d0 + j] = v[j];
    }
    __syncthreads();
    const int d = t >> 2, k0 = (t & 3) * 16;
    __bf16* dst = VTb + ((size_t)bh * DHEAD + d) * SLEN + kc * 64 + k0;
    BF8 o0, o1;
    #pragma unroll
    for (int kk = 0; kk < 8; ++kk) {
      o0.v[kk] = (__bf16)tf[k0 + kk][d];
      o1.v[kk] = (__bf16)tf[k0 + 8 + kk][d];
    }
    *(bf16x8*)dst = o0.v;
    *(bf16x8*)(dst + 8) = o1.v;
  } else {
    // K fp32 -> bf16, identical row-major layout
    const size_t base = (size_t)(b - 1536) * 4096;
    #pragma unroll
    for (int i = 0; i < 4; ++i) {
      size_t off = base + i * 1024 + t * 4;
      f32x4 v = *(const f32x4*)(Kp + off);
      bf16x4 o;
      #pragma unroll
      for (int j = 0; j < 4; ++j) o[j] = (__bf16)v[j];
      *(bf16x4*)(Kb + off) = o;
    }
  }
}

// ---------------- main kernel ----------------
struct SMem {
  __bf16 qt[QROWS][80];        // 2560 B, scaled Q tile (stride 80 -> bank-optimal b128)
  float red_m[4][16];          //  256 B
  float red_s[4][16];          //  256 B
  float ctxr[4][QROWS][72];    // 18432 B, per-wave PV partials
};                             // ~21.5 KB

template<bool STAGED>
__global__ __launch_bounds__(256, 4)
void attn_main(const float* __restrict__ Qp, const float* __restrict__ Kp,
               const float* __restrict__ Vp, const __bf16* __restrict__ Kb,
               const __bf16* __restrict__ VTb, const int* __restrict__ scale_p,
               float* __restrict__ out) {
  __shared__ SMem sm;
  const int tid  = threadIdx.x;
  const int w    = tid >> 6;     // wave 0..3, owns keys w*256..+255
  const int lane = tid & 63;
  const int quad = lane >> 4;
  const int c16  = lane & 15;

  // XCD-clustered decode: XCD (bid&7) owns 12 whole bh
  const int bid   = blockIdx.x;            // 0..6143
  const int slot  = bid >> 3;
  const int bh    = (bid & 7) * 12 + (slot >> 6);
  const int qbase = (slot & 63) * QROWS;

  int siv = *scale_p;
  float fs = (siv >= 1 && siv <= (1 << 24)) ? (float)siv : __int_as_float(siv);
  const float inv_scale = 1.0f / fs;

  // ---- stage Q tile (x 1/scale) as bf16 ----
  {
    int r = tid >> 4, d0 = (tid & 15) * 4;
    f32x4 qv = *(const f32x4*)(Qp + ((size_t)bh * SLEN + qbase + r) * DHEAD + d0);
    bf16x4 o;
    #pragma unroll
    for (int j = 0; j < 4; ++j) o[j] = (__bf16)(qv[j] * inv_scale);
    *(bf16x4*)&sm.qt[r][d0] = o;
  }
  __syncthreads();

  // Q^T B-frags: B[k=quad*8+j][n=c16] = Q[c16][k]
  BF8 qf0, qf1;
  qf0.v = *(const bf16x8*)&sm.qt[c16][quad * 8];
  qf1.v = *(const bf16x8*)&sm.qt[c16][32 + quad * 8];

  // ---- phase 1: S^T = K @ Q^T.  acc[mt] row=key quad*4+i, col=q-row c16 ----
  f32x4 acc[16];
  {
    f32x4 z = {0.0f, 0.0f, 0.0f, 0.0f};
    #pragma unroll
    for (int mt = 0; mt < 16; ++mt) acc[mt] = z;
  }
  const __bf16* Kbbase = STAGED ? Kb + ((size_t)bh * SLEN + w * 256) * DHEAD : nullptr;
  const float*  Kfbase = Kp + ((size_t)bh * SLEN + (size_t)w * 256) * DHEAD;
  #pragma unroll
  for (int mt = 0; mt < 16; ++mt) {
    int row = mt * 16 + c16;
    bf16x8 a0, a1;
    if constexpr (STAGED) {
      a0 = *(const bf16x8*)(Kbbase + (size_t)row * DHEAD + quad * 8);
      a1 = *(const bf16x8*)(Kbbase + (size_t)row * DHEAD + 32 + quad * 8);
    } else {
      const float* kr = Kfbase + (size_t)row * DHEAD + quad * 8;
      f32x4 x0 = *(const f32x4*)(kr);
      f32x4 x1 = *(const f32x4*)(kr + 4);
      f32x4 y0 = *(const f32x4*)(kr + 32);
      f32x4 y1 = *(const f32x4*)(kr + 36);
      #pragma unroll
      for (int j = 0; j < 4; ++j) {
        a0[j] = (__bf16)x0[j]; a0[j + 4] = (__bf16)x1[j];
        a1[j] = (__bf16)y0[j]; a1[j + 4] = (__bf16)y1[j];
      }
    }
    acc[mt] = __builtin_amdgcn_mfma_f32_16x16x32_bf16(a0, qf0.v, acc[mt], 0, 0, 0);
    acc[mt] = __builtin_amdgcn_mfma_f32_16x16x32_bf16(a1, qf1.v, acc[mt], 0, 0, 0);
  }

  // ---- softmax (per lane: one q-row = c16, 64 of the wave's 256 keys) ----
  float m;
  {
    float a = fmaxf(fmaxf(acc[0][0], acc[0][1]), fmaxf(acc[0][2], acc[0][3]));
    #pragma unroll
    for (int mt = 1; mt < 16; ++mt) {
      float b2 = fmaxf(fmaxf(acc[mt][0], acc[mt][1]), fmaxf(acc[mt][2], acc[mt][3]));
      a = fmaxf(a, b2);
    }
    a = fmaxf(a, __shfl_xor(a, 16));
    a = fmaxf(a, __shfl_xor(a, 32));
    if (lane < 16) sm.red_m[w][c16] = a;
  }
  __syncthreads();
  m = fmaxf(fmaxf(sm.red_m[0][c16], sm.red_m[1][c16]),
            fmaxf(sm.red_m[2][c16], sm.red_m[3][c16]));

  float s = 0.0f;
  #pragma unroll
  for (int mt = 0; mt < 16; ++mt)
    #pragma unroll
    for (int j = 0; j < 4; ++j) {
      float e = __expf(acc[mt][j] - m);
      acc[mt][j] = e;
      s += e;
    }
  s += __shfl_xor(s, 16);
  s += __shfl_xor(s, 32);
  if (lane < 16) sm.red_s[w][c16] = s;
  __syncthreads();
  const float inv = 1.0f / (sm.red_s[0][c16] + sm.red_s[1][c16] +
                            sm.red_s[2][c16] + sm.red_s[3][c16]);

  // ---- normalize, store probs (f32x4: 4 consecutive keys), build PV A-frags ----
  // kappa(t, s=q'*8+j) = w*256 + t*32 + q'*4 + (j&3) + 16*(j>>2)
  float* orow = out + ((size_t)bh * SLEN + qbase + c16) * SLEN + w * 256;
  BF8 pf[8];
  #pragma unroll
  for (int mt = 0; mt < 16; ++mt) {
    f32x4 p;
    #pragma unroll
    for (int j = 0; j < 4; ++j) p[j] = acc[mt][j] * inv;
    *(f32x4*)(orow + mt * 16 + quad * 4) = p;
    #pragma unroll
    for (int j = 0; j < 4; ++j)
      pf[mt >> 1].v[(mt & 1) * 4 + j] = (__bf16)p[j];
  }

  // ---- phase 2: partial context over this wave's 256 keys ----
  f32x4 ctx[4];
  {
    f32x4 z = {0.0f, 0.0f, 0.0f, 0.0f};
    #pragma unroll
    for (int dt = 0; dt < 4; ++dt) ctx[dt] = z;
  }
  const __bf16* Vt = STAGED ? VTb + (size_t)bh * DHEAD * SLEN : nullptr;
  #pragma unroll
  for (int t8 = 0; t8 < 8; ++t8) {
    int k0 = w * 256 + t8 * 32 + quad * 4;
    #pragma unroll
    for (int dt = 0; dt < 4; ++dt) {
      BF8 b;
      if constexpr (STAGED) {
        const __bf16* vr = Vt + (size_t)(dt * 16 + c16) * SLEN + k0;
        b.h[0] = *(const bf16x4*)(vr);
        b.h[1] = *(const bf16x4*)(vr + 16);
      } else {
        #pragma unroll
        for (int j = 0; j < 8; ++j)
          b.v[j] = (__bf16)Vp[((size_t)bh * SLEN + k0 + (j & 3) + 16 * (j >> 2)) * DHEAD +
                              dt * 16 + c16];
      }
      ctx[dt] = __builtin_amdgcn_mfma_f32_16x16x32_bf16(pf[t8].v, b.v, ctx[dt], 0, 0, 0);
    }
  }

  // ---- reduce 4 wave-partials, store context coalesced ----
  #pragma unroll
  for (int dt = 0; dt < 4; ++dt)
    #pragma unroll
    for (int i = 0; i < 4; ++i)
      sm.ctxr[w][quad * 4 + i][dt * 16 + c16] = ctx[dt][i];
  __syncthreads();
  {
    int q = tid >> 4, d4 = (tid & 15) * 4;
    f32x4 r0 = *(const f32x4*)&sm.ctxr[0][q][d4];
    f32x4 r1 = *(const f32x4*)&sm.ctxr[1][q][d4];
    f32x4 r2 = *(const f32x4*)&sm.ctxr[2][q][d4];
    f32x4 r3 = *(const f32x4*)&sm.ctxr[3][q][d4];
    f32x4 o;
    #pragma unroll
    for (int j = 0; j < 4; ++j) o[j] = (r0[j] + r1[j]) + (r2[j] + r3[j]);
    float* outC = out + (size_t)NBH * SLEN * SLEN;
    *(f32x4*)(outC + ((size_t)bh * SLEN + qbase + q) * DHEAD + d4) = o;
  }
}

extern "C" void kernel_launch(void* const* d_in, const int* in_sizes, int n_in,
                              void* d_out, int out_size, void* d_ws, size_t ws_size,
                              hipStream_t stream) {
  (void)in_sizes; (void)n_in; (void)out_size;
  const float* q = (const float*)d_in[0];
  const float* k = (const float*)d_in[1];
  const float* v = (const float*)d_in[2];
  const int* scale = (const int*)d_in[3];
  float* out = (float*)d_out;

  const bool staged = (d_ws != nullptr) && (ws_size >= (size_t)WS_BYTES);
  dim3 block(256);
  if (staged) {
    __bf16* Kb  = (__bf16*)d_ws;
    __bf16* VTb = Kb + KB_ELEMS;
    hipLaunchKernelGGL(prepass, dim3(3072), block, 0, stream, k, v, Kb, VTb);
    hipLaunchKernelGGL(attn_main<true>, dim3((SLEN / QROWS) * NBH), block, 0, stream,
                       q, k, v, Kb, VTb, scale, out);
  } else {
    hipLaunchKernelGGL(attn_main<false>, dim3((SLEN / QROWS) * NBH), block, 0, stream,
                       q, k, v, (const __bf16*)nullptr, (const __bf16*)nullptr, scale, out);
  }
}

// Round 4
// 634.508 us; speedup vs baseline: 1.1327x; 1.1327x over previous
//
#include <hip/hip_runtime.h>

// Scaled dot-product attention, B=8 H=12 S=1024 D=64, fp32 in/out.
// Outputs (concatenated in d_out): probs (B,H,S,S) then context (B,H,S,D).
//
// v5: write-stream-first. Diagnosis: v1/v3/v4 all pinned at ~1.6 TB/s
// effective because probs go out as 64B-per-row scattered segments.
//  - Probs stores via LDS transpose: each store instruction writes ONE
//    row-span = 1KB contiguous (fill-kernel-like). 2 rounds of 2 wave-spans
//    through a 34KB buffer unioned with ctxr. 2-way-max LDS banks.
//  - Prepass writes VT2 in MFMA-slot-permuted order tau: PV B-frag = one
//    b128 load (32 loads/wave, was 64 scattered b64).
//  - Keeps v4 core: S^T = K@Q^T (softmax in-lane, P stays in registers as
//    the PV A-operand), 16-row blocks, 4 waves, ws-staged bf16 K/VT2,
//    XCD-clustered bid decode, probs phase last.

#define SLEN 1024
#define DHEAD 64
#define NBH 96
#define QROWS 16

typedef __attribute__((ext_vector_type(4))) float f32x4;
typedef __attribute__((ext_vector_type(4))) __bf16 bf16x4;
typedef __attribute__((ext_vector_type(8))) __bf16 bf16x8;

union BF8 { bf16x8 v; bf16x4 h[2]; };

#define KB_ELEMS ((size_t)NBH * SLEN * DHEAD)   // 6291456
#define WS_BYTES (KB_ELEMS * 2 * 2)             // 25165824

// slot tau -> key (within a 64-key chunk); inverse of kappa packing:
// kappa(t, quad*8+e) = 32t + quad*4 + (e&3) + 16*(e>>2),  tau = 32t + quad*8 + e
__device__ __forceinline__ int keyof(int tau) {
  return 32 * (tau >> 5) + ((tau >> 3) & 3) * 4 + 16 * ((tau >> 2) & 1) + (tau & 3);
}

// ---------------- pre-pass: Kbf16 + slot-permuted VT2 bf16 into ws ----------------
__global__ __launch_bounds__(256)
void prepass(const float* __restrict__ Kp, const float* __restrict__ Vp,
             __bf16* __restrict__ Kb, __bf16* __restrict__ VTb) {
  __shared__ float tf[64][68];
  const int b = blockIdx.x, t = threadIdx.x;
  if (b < 1536) {
    // V transpose+permute: bh = b>>4, 64-key chunk kc = b&15 -> VT2[bh][d][tau]
    const int bh = b >> 4, kc = b & 15;
    const float* Vg = Vp + ((size_t)bh * SLEN + (size_t)kc * 64) * DHEAD;
    #pragma unroll
    for (int i = 0; i < 4; ++i) {
      int r = i * 16 + (t >> 4), d0 = (t & 15) * 4;
      f32x4 v = *(const f32x4*)(Vg + (size_t)r * DHEAD + d0);
      #pragma unroll
      for (int j = 0; j < 4; ++j) tf[r][d0 + j] = v[j];
    }
    __syncthreads();
    const int d = t >> 2, tb = (t & 3) * 16;
    __bf16* dst = VTb + ((size_t)bh * DHEAD + d) * SLEN + kc * 64 + tb;
    BF8 o0, o1;
    #pragma unroll
    for (int x = 0; x < 8; ++x) {
      o0.v[x] = (__bf16)tf[keyof(tb + x)][d];
      o1.v[x] = (__bf16)tf[keyof(tb + 8 + x)][d];
    }
    *(bf16x8*)dst = o0.v;
    *(bf16x8*)(dst + 8) = o1.v;
  } else {
    // K fp32 -> bf16, identical row-major layout
    const size_t base = (size_t)(b - 1536) * 4096;
    #pragma unroll
    for (int i = 0; i < 4; ++i) {
      size_t off = base + i * 1024 + t * 4;
      f32x4 v = *(const f32x4*)(Kp + off);
      bf16x4 o;
      #pragma unroll
      for (int j = 0; j < 4; ++j) o[j] = (__bf16)v[j];
      *(bf16x4*)(Kb + off) = o;
    }
  }
}

// ---------------- main kernel ----------------
struct SMem {
  __bf16 qt[QROWS][80];          // 2560 B, scaled Q tile
  float red_m[4][16];            //  256 B
  float red_s[4][16];            //  256 B
  union {
    float ctxr[4][QROWS][72];    // 18432 B, PV wave partials
    float plin[2][QROWS][268];   // 34304 B, probs row-linear staging
  } u;
};                               // ~37.4 KB -> 4 blocks/CU

template<bool STAGED>
__global__ __launch_bounds__(256, 4)
void attn_main(const float* __restrict__ Qp, const float* __restrict__ Kp,
               const float* __restrict__ Vp, const __bf16* __restrict__ Kb,
               const __bf16* __restrict__ VTb, const int* __restrict__ scale_p,
               float* __restrict__ out) {
  __shared__ SMem sm;
  const int tid  = threadIdx.x;
  const int w    = tid >> 6;     // wave 0..3, owns keys w*256..+255
  const int lane = tid & 63;
  const int quad = lane >> 4;
  const int c16  = lane & 15;

  // XCD-clustered decode: XCD (bid&7) owns 12 whole bh
  const int bid   = blockIdx.x;            // 0..6143
  const int slot  = bid >> 3;
  const int bh    = (bid & 7) * 12 + (slot >> 6);
  const int qbase = (slot & 63) * QROWS;

  int siv = *scale_p;
  float fs = (siv >= 1 && siv <= (1 << 24)) ? (float)siv : __int_as_float(siv);
  const float inv_scale = 1.0f / fs;

  // ---- stage Q tile (x 1/scale) as bf16 ----
  {
    int r = tid >> 4, d0 = (tid & 15) * 4;
    f32x4 qv = *(const f32x4*)(Qp + ((size_t)bh * SLEN + qbase + r) * DHEAD + d0);
    bf16x4 o;
    #pragma unroll
    for (int j = 0; j < 4; ++j) o[j] = (__bf16)(qv[j] * inv_scale);
    *(bf16x4*)&sm.qt[r][d0] = o;
  }
  __syncthreads();

  // Q^T B-frags: B[k=quad*8+j][n=c16] = Q[c16][k]
  BF8 qf0, qf1;
  qf0.v = *(const bf16x8*)&sm.qt[c16][quad * 8];
  qf1.v = *(const bf16x8*)&sm.qt[c16][32 + quad * 8];

  // ---- phase 1: S^T = K @ Q^T.  acc[mt] row=key mt*16+quad*4+i, col=q-row c16 ----
  f32x4 acc[16];
  {
    f32x4 z = {0.0f, 0.0f, 0.0f, 0.0f};
    #pragma unroll
    for (int mt = 0; mt < 16; ++mt) acc[mt] = z;
  }
  const __bf16* Kbbase = STAGED ? Kb + ((size_t)bh * SLEN + w * 256) * DHEAD : nullptr;
  const float*  Kfbase = Kp + ((size_t)bh * SLEN + (size_t)w * 256) * DHEAD;
  #pragma unroll
  for (int mt = 0; mt < 16; ++mt) {
    int row = mt * 16 + c16;
    bf16x8 a0, a1;
    if constexpr (STAGED) {
      a0 = *(const bf16x8*)(Kbbase + (size_t)row * DHEAD + quad * 8);
      a1 = *(const bf16x8*)(Kbbase + (size_t)row * DHEAD + 32 + quad * 8);
    } else {
      const float* kr = Kfbase + (size_t)row * DHEAD + quad * 8;
      f32x4 x0 = *(const f32x4*)(kr);
      f32x4 x1 = *(const f32x4*)(kr + 4);
      f32x4 y0 = *(const f32x4*)(kr + 32);
      f32x4 y1 = *(const f32x4*)(kr + 36);
      #pragma unroll
      for (int j = 0; j < 4; ++j) {
        a0[j] = (__bf16)x0[j]; a0[j + 4] = (__bf16)x1[j];
        a1[j] = (__bf16)y0[j]; a1[j + 4] = (__bf16)y1[j];
      }
    }
    acc[mt] = __builtin_amdgcn_mfma_f32_16x16x32_bf16(a0, qf0.v, acc[mt], 0, 0, 0);
    acc[mt] = __builtin_amdgcn_mfma_f32_16x16x32_bf16(a1, qf1.v, acc[mt], 0, 0, 0);
  }

  // ---- softmax (per lane: one q-row = c16, 64 of the wave's 256 keys) ----
  float m;
  {
    float a = fmaxf(fmaxf(acc[0][0], acc[0][1]), fmaxf(acc[0][2], acc[0][3]));
    #pragma unroll
    for (int mt = 1; mt < 16; ++mt) {
      float b2 = fmaxf(fmaxf(acc[mt][0], acc[mt][1]), fmaxf(acc[mt][2], acc[mt][3]));
      a = fmaxf(a, b2);
    }
    a = fmaxf(a, __shfl_xor(a, 16));
    a = fmaxf(a, __shfl_xor(a, 32));
    if (lane < 16) sm.red_m[w][c16] = a;
  }
  __syncthreads();
  m = fmaxf(fmaxf(sm.red_m[0][c16], sm.red_m[1][c16]),
            fmaxf(sm.red_m[2][c16], sm.red_m[3][c16]));

  float s = 0.0f;
  #pragma unroll
  for (int mt = 0; mt < 16; ++mt)
    #pragma unroll
    for (int j = 0; j < 4; ++j) {
      float e = __expf(acc[mt][j] - m);
      acc[mt][j] = e;
      s += e;
    }
  s += __shfl_xor(s, 16);
  s += __shfl_xor(s, 32);
  if (lane < 16) sm.red_s[w][c16] = s;
  __syncthreads();
  const float inv = 1.0f / (sm.red_s[0][c16] + sm.red_s[1][c16] +
                            sm.red_s[2][c16] + sm.red_s[3][c16]);

  // ---- normalize in regs; build PV A-frags ----
  // kappa(t, s=quad*8+e) = w*256 + 32t + quad*4 + (e&3) + 16*(e>>2)
  BF8 pf[8];
  #pragma unroll
  for (int mt = 0; mt < 16; ++mt) {
    #pragma unroll
    for (int j = 0; j < 4; ++j) {
      float p = acc[mt][j] * inv;
      acc[mt][j] = p;                       // kept for the probs phase
      pf[mt >> 1].v[(mt & 1) * 4 + j] = (__bf16)p;
    }
  }

  // ---- phase 2: partial context over this wave's 256 keys ----
  f32x4 ctx[4];
  {
    f32x4 z = {0.0f, 0.0f, 0.0f, 0.0f};
    #pragma unroll
    for (int dt = 0; dt < 4; ++dt) ctx[dt] = z;
  }
  const __bf16* Vt = STAGED ? VTb + (size_t)bh * DHEAD * SLEN : nullptr;
  #pragma unroll
  for (int t8 = 0; t8 < 8; ++t8) {
    #pragma unroll
    for (int dt = 0; dt < 4; ++dt) {
      BF8 b;
      if constexpr (STAGED) {
        // slot-permuted VT2: one b128 per fragment
        b.v = *(const bf16x8*)(Vt + (size_t)(dt * 16 + c16) * SLEN +
                               w * 256 + t8 * 32 + quad * 8);
      } else {
        int k0 = w * 256 + t8 * 32 + quad * 4;
        #pragma unroll
        for (int j = 0; j < 8; ++j)
          b.v[j] = (__bf16)Vp[((size_t)bh * SLEN + k0 + (j & 3) + 16 * (j >> 2)) * DHEAD +
                              dt * 16 + c16];
      }
      ctx[dt] = __builtin_amdgcn_mfma_f32_16x16x32_bf16(pf[t8].v, b.v, ctx[dt], 0, 0, 0);
    }
  }

  // ---- reduce 4 wave-partials, store context coalesced ----
  #pragma unroll
  for (int dt = 0; dt < 4; ++dt)
    #pragma unroll
    for (int i = 0; i < 4; ++i)
      sm.u.ctxr[w][quad * 4 + i][dt * 16 + c16] = ctx[dt][i];
  __syncthreads();
  {
    int q = tid >> 4, d4 = (tid & 15) * 4;
    f32x4 r0 = *(const f32x4*)&sm.u.ctxr[0][q][d4];
    f32x4 r1 = *(const f32x4*)&sm.u.ctxr[1][q][d4];
    f32x4 r2 = *(const f32x4*)&sm.u.ctxr[2][q][d4];
    f32x4 r3 = *(const f32x4*)&sm.u.ctxr[3][q][d4];
    f32x4 o;
    #pragma unroll
    for (int j = 0; j < 4; ++j) o[j] = (r0[j] + r1[j]) + (r2[j] + r3[j]);
    float* outC = out + (size_t)NBH * SLEN * SLEN;
    *(f32x4*)(outC + ((size_t)bh * SLEN + qbase + q) * DHEAD + d4) = o;
  }
  __syncthreads();   // ctxr reads done block-wide before plin overwrites it

  // ---- probs: LDS-transpose to row-linear, 1KB-contiguous store per instr ----
  // Round r: waves {2r, 2r+1} deposit their spans; whole block stores them.
  #pragma unroll
  for (int r = 0; r < 2; ++r) {
    if ((w >> 1) == r) {
      #pragma unroll
      for (int mt = 0; mt < 16; ++mt)
        *(f32x4*)&sm.u.plin[w & 1][c16][mt * 16 + quad * 4] = acc[mt];
    }
    __syncthreads();
    #pragma unroll
    for (int jj = 0; jj < 8; ++jj) {
      int idx = w * 8 + jj;              // 0..31 -> (half, row)
      int h = idx >> 4, row = idx & 15;
      f32x4 vls = *(const f32x4*)&sm.u.plin[h][row][lane * 4];
      *(f32x4*)(out + ((size_t)bh * SLEN + qbase + row) * SLEN +
                (size_t)(r * 2 + h) * 256 + lane * 4) = vls;
    }
    if (r == 0) __syncthreads();         // reads done before round-1 deposits
  }
}

extern "C" void kernel_launch(void* const* d_in, const int* in_sizes, int n_in,
                              void* d_out, int out_size, void* d_ws, size_t ws_size,
                              hipStream_t stream) {
  (void)in_sizes; (void)n_in; (void)out_size;
  const float* q = (const float*)d_in[0];
  const float* k = (const float*)d_in[1];
  const float* v = (const float*)d_in[2];
  const int* scale = (const int*)d_in[3];
  float* out = (float*)d_out;

  const bool staged = (d_ws != nullptr) && (ws_size >= (size_t)WS_BYTES);
  dim3 block(256);
  if (staged) {
    __bf16* Kb  = (__bf16*)d_ws;
    __bf16* VTb = Kb + KB_ELEMS;
    hipLaunchKernelGGL(prepass, dim3(3072), block, 0, stream, k, v, Kb, VTb);
    hipLaunchKernelGGL(attn_main<true>, dim3((SLEN / QROWS) * NBH), block, 0, stream,
                       q, k, v, Kb, VTb, scale, out);
  } else {
    hipLaunchKernelGGL(attn_main<false>, dim3((SLEN / QROWS) * NBH), block, 0, stream,
                       q, k, v, (const __bf16*)nullptr, (const __bf16*)nullptr, scale, out);
  }
}

// Round 5
// 626.702 us; speedup vs baseline: 1.1468x; 1.0125x over previous
//
#include <hip/hip_runtime.h>

// Scaled dot-product attention, B=8 H=12 S=1024 D=64, fp32 in/out.
// Outputs (concatenated in d_out): probs (B,H,S,S) then context (B,H,S,D).
//
// v6: stall-chain restructure on top of v5's row-linear probs stores.
//  - 8 waves x 128 keys (512 thr): acc = 8 f32x4/lane (was 16) -> no AGPR
//    shuttling through softmax, VGPR well under the 128 cap.
//  - Probs stores interleaved INTO the PV loop, per-t8, issued AFTER that
//    t8's B-loads: vmcnt is in-order, so awaiting the loads leaves the
//    newer stores outstanding; MFMAs run while stores drain (v5 issued all
//    stores before all loads -> PV serialized behind the store stream).
//  - s_setprio(1) around MFMA clusters (T5).
//  - Single plin deposit round (all 8 waves), stride 1028 f32 (2-way max
//    banks on deposit, balanced on read); union with ctxr (time-disjoint,
//    barrier-separated). LDS ~69.4 KB -> 2 blocks/CU, 16 waves/CU.
//  - Keeps: S^T=K@Q^T core, P in regs as PV A-operand, ws-staged bf16
//    K/VT2 (slot-permuted), XCD-clustered bid decode (6144%8==0 bijective).

#define SLEN 1024
#define DHEAD 64
#define NBH 96
#define QROWS 16

typedef __attribute__((ext_vector_type(4))) float f32x4;
typedef __attribute__((ext_vector_type(4))) __bf16 bf16x4;
typedef __attribute__((ext_vector_type(8))) __bf16 bf16x8;

union BF8 { bf16x8 v; bf16x4 h[2]; };

#define KB_ELEMS ((size_t)NBH * SLEN * DHEAD)   // 6291456
#define WS_BYTES (KB_ELEMS * 2 * 2)             // 25165824

// slot tau -> key (within a 64-key chunk); inverse of kappa packing:
// kappa(t, quad*8+e) = 32t + quad*4 + (e&3) + 16*(e>>2),  tau = 32t + quad*8 + e
__device__ __forceinline__ int keyof(int tau) {
  return 32 * (tau >> 5) + ((tau >> 3) & 3) * 4 + 16 * ((tau >> 2) & 1) + (tau & 3);
}

// ---------------- pre-pass: Kbf16 + slot-permuted VT2 bf16 into ws ----------------
__global__ __launch_bounds__(256)
void prepass(const float* __restrict__ Kp, const float* __restrict__ Vp,
             __bf16* __restrict__ Kb, __bf16* __restrict__ VTb) {
  __shared__ float tf[64][68];
  const int b = blockIdx.x, t = threadIdx.x;
  if (b < 1536) {
    // V transpose+permute: bh = b>>4, 64-key chunk kc = b&15 -> VT2[bh][d][tau]
    const int bh = b >> 4, kc = b & 15;
    const float* Vg = Vp + ((size_t)bh * SLEN + (size_t)kc * 64) * DHEAD;
    #pragma unroll
    for (int i = 0; i < 4; ++i) {
      int r = i * 16 + (t >> 4), d0 = (t & 15) * 4;
      f32x4 v = *(const f32x4*)(Vg + (size_t)r * DHEAD + d0);
      #pragma unroll
      for (int j = 0; j < 4; ++j) tf[r][d0 + j] = v[j];
    }
    __syncthreads();
    const int d = t >> 2, tb = (t & 3) * 16;
    __bf16* dst = VTb + ((size_t)bh * DHEAD + d) * SLEN + kc * 64 + tb;
    BF8 o0, o1;
    #pragma unroll
    for (int x = 0; x < 8; ++x) {
      o0.v[x] = (__bf16)tf[keyof(tb + x)][d];
      o1.v[x] = (__bf16)tf[keyof(tb + 8 + x)][d];
    }
    *(bf16x8*)dst = o0.v;
    *(bf16x8*)(dst + 8) = o1.v;
  } else {
    // K fp32 -> bf16, identical row-major layout
    const size_t base = (size_t)(b - 1536) * 4096;
    #pragma unroll
    for (int i = 0; i < 4; ++i) {
      size_t off = base + i * 1024 + t * 4;
      f32x4 v = *(const f32x4*)(Kp + off);
      bf16x4 o;
      #pragma unroll
      for (int j = 0; j < 4; ++j) o[j] = (__bf16)v[j];
      *(bf16x4*)(Kb + off) = o;
    }
  }
}

// ---------------- main kernel ----------------
struct SMem {
  union {
    float plin[QROWS][1028];     // 65792 B  probs row-linear staging
    float ctxr[8][QROWS][68];    // 34816 B  PV wave partials (after plin reads)
  } u;
  __bf16 qt[QROWS][80];          //  2560 B  scaled Q tile
  float red_m[8][16];            //   512 B
  float red_s[8][16];            //   512 B
};                               // ~69.4 KB -> 2 blocks/CU (16 waves)

template<bool STAGED>
__global__ __launch_bounds__(512, 4)
void attn_main(const float* __restrict__ Qp, const float* __restrict__ Kp,
               const float* __restrict__ Vp, const __bf16* __restrict__ Kb,
               const __bf16* __restrict__ VTb, const int* __restrict__ scale_p,
               float* __restrict__ out) {
  __shared__ SMem sm;
  const int tid  = threadIdx.x;
  const int w    = tid >> 6;     // wave 0..7, owns keys w*128..+127
  const int lane = tid & 63;
  const int quad = lane >> 4;
  const int c16  = lane & 15;

  // XCD-clustered decode: XCD (bid&7) owns 12 whole bh (6144%8==0: bijective)
  const int bid   = blockIdx.x;            // 0..6143
  const int slot  = bid >> 3;
  const int bh    = (bid & 7) * 12 + (slot >> 6);
  const int qbase = (slot & 63) * QROWS;

  int siv = *scale_p;
  float fs = (siv >= 1 && siv <= (1 << 24)) ? (float)siv : __int_as_float(siv);
  const float inv_scale = 1.0f / fs;

  // ---- stage Q tile (x 1/scale) as bf16 ----
  if (tid < 256) {
    int r = tid >> 4, d0 = (tid & 15) * 4;
    f32x4 qv = *(const f32x4*)(Qp + ((size_t)bh * SLEN + qbase + r) * DHEAD + d0);
    bf16x4 o;
    #pragma unroll
    for (int j = 0; j < 4; ++j) o[j] = (__bf16)(qv[j] * inv_scale);
    *(bf16x4*)&sm.qt[r][d0] = o;
  }
  __syncthreads();

  // Q^T B-frags: B[k=quad*8+j][n=c16] = Q[c16][k]
  BF8 qf0, qf1;
  qf0.v = *(const bf16x8*)&sm.qt[c16][quad * 8];
  qf1.v = *(const bf16x8*)&sm.qt[c16][32 + quad * 8];

  // ---- phase 1: S^T = K @ Q^T.  acc[mt] row=key w*128+mt*16+quad*4+i, col=q c16 ----
  f32x4 acc[8];
  {
    f32x4 z = {0.0f, 0.0f, 0.0f, 0.0f};
    #pragma unroll
    for (int mt = 0; mt < 8; ++mt) acc[mt] = z;
  }
  const __bf16* Kbbase = STAGED ? Kb + ((size_t)bh * SLEN + w * 128) * DHEAD : nullptr;
  const float*  Kfbase = Kp + ((size_t)bh * SLEN + (size_t)w * 128) * DHEAD;
  #pragma unroll
  for (int mt = 0; mt < 8; ++mt) {
    int row = mt * 16 + c16;
    bf16x8 a0, a1;
    if constexpr (STAGED) {
      a0 = *(const bf16x8*)(Kbbase + (size_t)row * DHEAD + quad * 8);
      a1 = *(const bf16x8*)(Kbbase + (size_t)row * DHEAD + 32 + quad * 8);
    } else {
      const float* kr = Kfbase + (size_t)row * DHEAD + quad * 8;
      f32x4 x0 = *(const f32x4*)(kr);
      f32x4 x1 = *(const f32x4*)(kr + 4);
      f32x4 y0 = *(const f32x4*)(kr + 32);
      f32x4 y1 = *(const f32x4*)(kr + 36);
      #pragma unroll
      for (int j = 0; j < 4; ++j) {
        a0[j] = (__bf16)x0[j]; a0[j + 4] = (__bf16)x1[j];
        a1[j] = (__bf16)y0[j]; a1[j + 4] = (__bf16)y1[j];
      }
    }
    __builtin_amdgcn_s_setprio(1);
    acc[mt] = __builtin_amdgcn_mfma_f32_16x16x32_bf16(a0, qf0.v, acc[mt], 0, 0, 0);
    acc[mt] = __builtin_amdgcn_mfma_f32_16x16x32_bf16(a1, qf1.v, acc[mt], 0, 0, 0);
    __builtin_amdgcn_s_setprio(0);
  }

  // ---- softmax (per lane: one q-row = c16, 32 of the wave's 128 keys) ----
  float m;
  {
    float a = fmaxf(fmaxf(acc[0][0], acc[0][1]), fmaxf(acc[0][2], acc[0][3]));
    #pragma unroll
    for (int mt = 1; mt < 8; ++mt) {
      float b2 = fmaxf(fmaxf(acc[mt][0], acc[mt][1]), fmaxf(acc[mt][2], acc[mt][3]));
      a = fmaxf(a, b2);
    }
    a = fmaxf(a, __shfl_xor(a, 16));
    a = fmaxf(a, __shfl_xor(a, 32));
    if (lane < 16) sm.red_m[w][c16] = a;
  }
  __syncthreads();
  {
    float m0 = fmaxf(sm.red_m[0][c16], sm.red_m[1][c16]);
    float m1 = fmaxf(sm.red_m[2][c16], sm.red_m[3][c16]);
    float m2 = fmaxf(sm.red_m[4][c16], sm.red_m[5][c16]);
    float m3 = fmaxf(sm.red_m[6][c16], sm.red_m[7][c16]);
    m = fmaxf(fmaxf(m0, m1), fmaxf(m2, m3));
  }

  float s = 0.0f;
  #pragma unroll
  for (int mt = 0; mt < 8; ++mt)
    #pragma unroll
    for (int j = 0; j < 4; ++j) {
      float e = __expf(acc[mt][j] - m);
      acc[mt][j] = e;
      s += e;
    }
  s += __shfl_xor(s, 16);
  s += __shfl_xor(s, 32);
  if (lane < 16) sm.red_s[w][c16] = s;
  __syncthreads();
  const float inv = 1.0f / (((sm.red_s[0][c16] + sm.red_s[1][c16]) +
                             (sm.red_s[2][c16] + sm.red_s[3][c16])) +
                            ((sm.red_s[4][c16] + sm.red_s[5][c16]) +
                             (sm.red_s[6][c16] + sm.red_s[7][c16])));

  // ---- normalize: deposit plin (f32x4, 2-way max banks) + build PV A-frags ----
  BF8 pf[4];
  #pragma unroll
  for (int mt = 0; mt < 8; ++mt) {
    f32x4 p;
    #pragma unroll
    for (int j = 0; j < 4; ++j) p[j] = acc[mt][j] * inv;
    *(f32x4*)&sm.u.plin[c16][w * 128 + mt * 16 + quad * 4] = p;
    #pragma unroll
    for (int j = 0; j < 4; ++j)
      pf[mt >> 1].v[(mt & 1) * 4 + j] = (__bf16)p[j];
  }
  __syncthreads();   // plin complete

  // ---- phase 2: PV with probs stores interleaved per-t8 ----
  // Per t8: {4 B-loads, 2 probs-store instrs, 4 MFMA}. Loads precede stores,
  // so the MFMA's vmcnt wait (in-order counter) retires only the loads and
  // leaves the stores in flight; they drain under subsequent MFMAs.
  f32x4 ctx[4];
  {
    f32x4 z = {0.0f, 0.0f, 0.0f, 0.0f};
    #pragma unroll
    for (int dt = 0; dt < 4; ++dt) ctx[dt] = z;
  }
  const __bf16* Vt = STAGED ? VTb + (size_t)bh * DHEAD * SLEN : nullptr;
  const int srow2 = tid >> 8;            // probs-store helper: 0..1
  const int scol4 = (tid & 255) * 4;
  #pragma unroll
  for (int t8 = 0; t8 < 4; ++t8) {
    BF8 b[4];
    if constexpr (STAGED) {
      #pragma unroll
      for (int dt = 0; dt < 4; ++dt)
        b[dt].v = *(const bf16x8*)(Vt + (size_t)(dt * 16 + c16) * SLEN +
                                   w * 128 + t8 * 32 + quad * 8);
    } else {
      int k0 = w * 128 + t8 * 32 + quad * 4;
      #pragma unroll
      for (int dt = 0; dt < 4; ++dt)
        #pragma unroll
        for (int j = 0; j < 8; ++j)
          b[dt].v[j] = (__bf16)Vp[((size_t)bh * SLEN + k0 + (j & 3) + 16 * (j >> 2)) * DHEAD +
                                  dt * 16 + c16];
    }
    // two probs rows out (1KB-contiguous per 256-thread group)
    #pragma unroll
    for (int h = 0; h < 2; ++h) {
      int row = (t8 * 2 + h) * 2 + srow2;
      f32x4 vls = *(const f32x4*)&sm.u.plin[row][scol4];
      *(f32x4*)(out + ((size_t)bh * SLEN + qbase + row) * SLEN + scol4) = vls;
    }
    __builtin_amdgcn_s_setprio(1);
    #pragma unroll
    for (int dt = 0; dt < 4; ++dt)
      ctx[dt] = __builtin_amdgcn_mfma_f32_16x16x32_bf16(pf[t8].v, b[dt].v, ctx[dt], 0, 0, 0);
    __builtin_amdgcn_s_setprio(0);
  }
  __syncthreads();   // plin reads done everywhere; drains residual stores

  // ---- reduce 8 wave-partials, store context coalesced ----
  #pragma unroll
  for (int dt = 0; dt < 4; ++dt)
    #pragma unroll
    for (int i = 0; i < 4; ++i)
      sm.u.ctxr[w][quad * 4 + i][dt * 16 + c16] = ctx[dt][i];
  __syncthreads();
  if (tid < 256) {
    int q = tid >> 4, d4 = (tid & 15) * 4;
    f32x4 o = *(const f32x4*)&sm.u.ctxr[0][q][d4];
    #pragma unroll
    for (int w2 = 1; w2 < 8; ++w2) {
      f32x4 r = *(const f32x4*)&sm.u.ctxr[w2][q][d4];
      #pragma unroll
      for (int j = 0; j < 4; ++j) o[j] += r[j];
    }
    float* outC = out + (size_t)NBH * SLEN * SLEN;
    *(f32x4*)(outC + ((size_t)bh * SLEN + qbase + q) * DHEAD + d4) = o;
  }
}

extern "C" void kernel_launch(void* const* d_in, const int* in_sizes, int n_in,
                              void* d_out, int out_size, void* d_ws, size_t ws_size,
                              hipStream_t stream) {
  (void)in_sizes; (void)n_in; (void)out_size;
  const float* q = (const float*)d_in[0];
  const float* k = (const float*)d_in[1];
  const float* v = (const float*)d_in[2];
  const int* scale = (const int*)d_in[3];
  float* out = (float*)d_out;

  const bool staged = (d_ws != nullptr) && (ws_size >= (size_t)WS_BYTES);
  if (staged) {
    __bf16* Kb  = (__bf16*)d_ws;
    __bf16* VTb = Kb + KB_ELEMS;
    hipLaunchKernelGGL(prepass, dim3(3072), dim3(256), 0, stream, k, v, Kb, VTb);
    hipLaunchKernelGGL(attn_main<true>, dim3((SLEN / QROWS) * NBH), dim3(512), 0, stream,
                       q, k, v, Kb, VTb, scale, out);
  } else {
    hipLaunchKernelGGL(attn_main<false>, dim3((SLEN / QROWS) * NBH), dim3(512), 0, stream,
                       q, k, v, (const __bf16*)nullptr, (const __bf16*)nullptr, scale, out);
  }
}